// Round 2
// 1212.696 us; speedup vs baseline: 1.8377x; 1.8377x over previous
//
#include <hip/hip_runtime.h>
#include <math.h>

#define BATCH 524288
#define DIN 118
#define TPB 512
#define NBLK (BATCH / TPB)   // 1024 blocks
#define CSTR 65              // LDS column stride (floats), 65 -> conflict-free

__device__ __forceinline__ float fast_tanh(float v) {
    float a = fabsf(v);
    float e = __expf(-2.0f * a);
    float t = 1.0f - 2.0f * e / (1.0f + e);
    return copysignf(t, v);
}

__device__ __forceinline__ void wave_reduce_store(double v, double* dst, int lane) {
    #pragma unroll
    for (int off = 32; off > 0; off >>= 1) v += __shfl_down(v, off);
    if (lane == 0) *dst = v;
}

__global__ __launch_bounds__(TPB, 4) void fwd_kernel(
    const float* __restrict__ x,
    const float* __restrict__ eW0, const float* __restrict__ eb0,
    const float* __restrict__ eW1, const float* __restrict__ eb1,
    const float* __restrict__ eW2, const float* __restrict__ eb2,
    const float* __restrict__ eW3, const float* __restrict__ eb3,
    const float* __restrict__ dW0, const float* __restrict__ db0,
    const float* __restrict__ dW1, const float* __restrict__ db1,
    const float* __restrict__ dW2, const float* __restrict__ db2,
    const float* __restrict__ dW3, const float* __restrict__ db3,
    const float* __restrict__ tW0, const float* __restrict__ tb0,
    const float* __restrict__ tW1, const float* __restrict__ tb1,
    float* __restrict__ dec_out, float* __restrict__ zbuf,
    double* __restrict__ acc)
{
    // per-wave transposed x/dec tile: [16 cols][64 rows], stride 65
    __shared__ float xs[8][16 * CSTR];
    __shared__ double sred[8][30];

    const int tid = threadIdx.x;
    const int w = tid >> 6;
    const int lane = tid & 63;
    const int rowbase = blockIdx.x * TPB + (w << 6);
    float* __restrict__ xw = xs[w];
    const float* __restrict__ xrow = x + (size_t)rowbase * DIN;

    // ---- encoder layer 0 (118 -> 60), chunked LDS staging, x stats ----
    float h[60];
    #pragma unroll
    for (int j4 = 0; j4 < 15; ++j4) {
        float4 bv = ((const float4*)eb0)[j4];
        h[4 * j4 + 0] = bv.x; h[4 * j4 + 1] = bv.y;
        h[4 * j4 + 2] = bv.z; h[4 * j4 + 3] = bv.w;
    }
    float sx = 0.f, sx2 = 0.f;

    #pragma unroll 1
    for (int q = 0; q < 7; ++q) {
        const int c0 = q << 4;
        // stage 16 cols x 64 rows, coalesced float2, transposed into LDS
        #pragma unroll
        for (int k = 0; k < 8; ++k) {
            int flat = lane + (k << 6);
            int r = flat >> 3, c2 = flat & 7;
            float2 v = *(const float2*)(xrow + (size_t)r * DIN + c0 + (c2 << 1));
            xw[(c2 << 1) * CSTR + r] = v.x;
            xw[((c2 << 1) + 1) * CSTR + r] = v.y;
        }
        #pragma unroll 2
        for (int cc = 0; cc < 16; ++cc) {
            float xc = xw[cc * CSTR + lane];
            sx += xc; sx2 = fmaf(xc, xc, sx2);
            const float4* wr = (const float4*)(eW0 + (c0 + cc) * 60);
            #pragma unroll
            for (int j4 = 0; j4 < 15; ++j4) {
                float4 wv = wr[j4];
                h[4 * j4 + 0] = fmaf(xc, wv.x, h[4 * j4 + 0]);
                h[4 * j4 + 1] = fmaf(xc, wv.y, h[4 * j4 + 1]);
                h[4 * j4 + 2] = fmaf(xc, wv.z, h[4 * j4 + 2]);
                h[4 * j4 + 3] = fmaf(xc, wv.w, h[4 * j4 + 3]);
            }
        }
    }
    { // tail: cols 112..117 (6 cols)
        #pragma unroll
        for (int k = 0; k < 3; ++k) {
            int flat = lane + (k << 6);
            int r = flat / 3, c2 = flat % 3;
            float2 v = *(const float2*)(xrow + (size_t)r * DIN + 112 + (c2 << 1));
            xw[(c2 << 1) * CSTR + r] = v.x;
            xw[((c2 << 1) + 1) * CSTR + r] = v.y;
        }
        #pragma unroll
        for (int cc = 0; cc < 6; ++cc) {
            float xc = xw[cc * CSTR + lane];
            sx += xc; sx2 = fmaf(xc, xc, sx2);
            const float4* wr = (const float4*)(eW0 + (112 + cc) * 60);
            #pragma unroll
            for (int j4 = 0; j4 < 15; ++j4) {
                float4 wv = wr[j4];
                h[4 * j4 + 0] = fmaf(xc, wv.x, h[4 * j4 + 0]);
                h[4 * j4 + 1] = fmaf(xc, wv.y, h[4 * j4 + 1]);
                h[4 * j4 + 2] = fmaf(xc, wv.z, h[4 * j4 + 2]);
                h[4 * j4 + 3] = fmaf(xc, wv.w, h[4 * j4 + 3]);
            }
        }
    }
    #pragma unroll
    for (int j = 0; j < 60; ++j) h[j] = fmaxf(h[j], 0.f);

    // ---- encoder layer 1 (60 -> 30) relu, outer-product ----
    float h2[30];
    #pragma unroll
    for (int j = 0; j < 30; ++j) h2[j] = eb1[j];
    #pragma unroll
    for (int i = 0; i < 60; ++i) {
        float hi = h[i];
        const float2* wr = (const float2*)(eW1 + i * 30);
        #pragma unroll
        for (int j2 = 0; j2 < 15; ++j2) {
            float2 wv = wr[j2];
            h2[2 * j2 + 0] = fmaf(hi, wv.x, h2[2 * j2 + 0]);
            h2[2 * j2 + 1] = fmaf(hi, wv.y, h2[2 * j2 + 1]);
        }
    }
    #pragma unroll
    for (int j = 0; j < 30; ++j) h2[j] = fmaxf(h2[j], 0.f);

    // ---- encoder layer 2 (30 -> 10) relu ----
    float h3[10];
    #pragma unroll
    for (int j = 0; j < 10; ++j) h3[j] = eb2[j];
    #pragma unroll
    for (int i = 0; i < 30; ++i) {
        float hi = h2[i];
        const float2* wr = (const float2*)(eW2 + i * 10);
        #pragma unroll
        for (int j2 = 0; j2 < 5; ++j2) {
            float2 wv = wr[j2];
            h3[2 * j2 + 0] = fmaf(hi, wv.x, h3[2 * j2 + 0]);
            h3[2 * j2 + 1] = fmaf(hi, wv.y, h3[2 * j2 + 1]);
        }
    }
    #pragma unroll
    for (int j = 0; j < 10; ++j) h3[j] = fmaxf(h3[j], 0.f);

    // ---- encoder layer 3 (10 -> 1) linear ----
    float enc = eb3[0];
    #pragma unroll
    for (int i = 0; i < 10; ++i) enc = fmaf(h3[i], eW3[i], enc);

    // ---- decoder layer 0 (1 -> 10) tanh ----
    float g1[10];
    #pragma unroll
    for (int j = 0; j < 10; ++j) g1[j] = fast_tanh(fmaf(enc, dW0[j], db0[j]));

    // ---- decoder layer 1 (10 -> 30) tanh, outer-product ----
    float g2[30];
    #pragma unroll
    for (int j = 0; j < 30; ++j) g2[j] = db1[j];
    #pragma unroll
    for (int i = 0; i < 10; ++i) {
        float gi = g1[i];
        const float2* wr = (const float2*)(dW1 + i * 30);
        #pragma unroll
        for (int j2 = 0; j2 < 15; ++j2) {
            float2 wv = wr[j2];
            g2[2 * j2 + 0] = fmaf(gi, wv.x, g2[2 * j2 + 0]);
            g2[2 * j2 + 1] = fmaf(gi, wv.y, g2[2 * j2 + 1]);
        }
    }
    #pragma unroll
    for (int j = 0; j < 30; ++j) g2[j] = fast_tanh(g2[j]);

    // ---- decoder layer 2 (30 -> 60) tanh, outer-product ----
    float g3[60];
    #pragma unroll
    for (int j4 = 0; j4 < 15; ++j4) {
        float4 bv = ((const float4*)db2)[j4];
        g3[4 * j4 + 0] = bv.x; g3[4 * j4 + 1] = bv.y;
        g3[4 * j4 + 2] = bv.z; g3[4 * j4 + 3] = bv.w;
    }
    #pragma unroll
    for (int i = 0; i < 30; ++i) {
        float gi = g2[i];
        const float4* wr = (const float4*)(dW2 + i * 60);
        #pragma unroll
        for (int j4 = 0; j4 < 15; ++j4) {
            float4 wv = wr[j4];
            g3[4 * j4 + 0] = fmaf(gi, wv.x, g3[4 * j4 + 0]);
            g3[4 * j4 + 1] = fmaf(gi, wv.y, g3[4 * j4 + 1]);
            g3[4 * j4 + 2] = fmaf(gi, wv.z, g3[4 * j4 + 2]);
            g3[4 * j4 + 3] = fmaf(gi, wv.w, g3[4 * j4 + 3]);
        }
    }
    #pragma unroll
    for (int j = 0; j < 60; ++j) g3[j] = fast_tanh(g3[j]);

    // ---- decoder layer 3 (60 -> 118), chunked: re-stage x, write dec via LDS ----
    float dotxd = 0.f, sd2 = 0.f, sdf2 = 0.f;
    float* __restrict__ drow = dec_out + (size_t)rowbase * DIN;

    #pragma unroll 1
    for (int q = 0; q < 7; ++q) {
        const int c0 = q << 4;
        // stage x chunk (coalesced)
        #pragma unroll
        for (int k = 0; k < 8; ++k) {
            int flat = lane + (k << 6);
            int r = flat >> 3, c2 = flat & 7;
            float2 v = *(const float2*)(xrow + (size_t)r * DIN + c0 + (c2 << 1));
            xw[(c2 << 1) * CSTR + r] = v.x;
            xw[((c2 << 1) + 1) * CSTR + r] = v.y;
        }
        // 16 output columns, outer-product over g3
        float acc16[16];
        #pragma unroll
        for (int j4 = 0; j4 < 4; ++j4) {
            float4 bv = *(const float4*)(db3 + c0 + 4 * j4);
            acc16[4 * j4 + 0] = bv.x; acc16[4 * j4 + 1] = bv.y;
            acc16[4 * j4 + 2] = bv.z; acc16[4 * j4 + 3] = bv.w;
        }
        #pragma unroll
        for (int i = 0; i < 60; ++i) {
            float gi = g3[i];
            const float2* wr = (const float2*)(dW3 + i * DIN + c0);
            #pragma unroll
            for (int j2 = 0; j2 < 8; ++j2) {
                float2 wv = wr[j2];
                acc16[2 * j2 + 0] = fmaf(gi, wv.x, acc16[2 * j2 + 0]);
                acc16[2 * j2 + 1] = fmaf(gi, wv.y, acc16[2 * j2 + 1]);
            }
        }
        // stats + overwrite LDS with dec values
        #pragma unroll
        for (int cc = 0; cc < 16; ++cc) {
            float xc = xw[cc * CSTR + lane];
            float a = acc16[cc];
            dotxd = fmaf(xc, a, dotxd);
            sd2 = fmaf(a, a, sd2);
            float u = xc - a;
            sdf2 = fmaf(u, u, sdf2);
            xw[cc * CSTR + lane] = a;
        }
        // flush dec chunk (coalesced)
        #pragma unroll
        for (int k = 0; k < 8; ++k) {
            int flat = lane + (k << 6);
            int r = flat >> 3, c2 = flat & 7;
            float2 o;
            o.x = xw[(c2 << 1) * CSTR + r];
            o.y = xw[((c2 << 1) + 1) * CSTR + r];
            *(float2*)(drow + (size_t)r * DIN + c0 + (c2 << 1)) = o;
        }
    }
    { // tail: cols 112..117
        #pragma unroll
        for (int k = 0; k < 3; ++k) {
            int flat = lane + (k << 6);
            int r = flat / 3, c2 = flat % 3;
            float2 v = *(const float2*)(xrow + (size_t)r * DIN + 112 + (c2 << 1));
            xw[(c2 << 1) * CSTR + r] = v.x;
            xw[((c2 << 1) + 1) * CSTR + r] = v.y;
        }
        float acc6[6];
        {
            float4 bv = *(const float4*)(db3 + 112);
            float2 b2 = *(const float2*)(db3 + 116);
            acc6[0] = bv.x; acc6[1] = bv.y; acc6[2] = bv.z; acc6[3] = bv.w;
            acc6[4] = b2.x; acc6[5] = b2.y;
        }
        #pragma unroll
        for (int i = 0; i < 60; ++i) {
            float gi = g3[i];
            const float2* wr = (const float2*)(dW3 + i * DIN + 112);
            #pragma unroll
            for (int j2 = 0; j2 < 3; ++j2) {
                float2 wv = wr[j2];
                acc6[2 * j2 + 0] = fmaf(gi, wv.x, acc6[2 * j2 + 0]);
                acc6[2 * j2 + 1] = fmaf(gi, wv.y, acc6[2 * j2 + 1]);
            }
        }
        #pragma unroll
        for (int cc = 0; cc < 6; ++cc) {
            float xc = xw[cc * CSTR + lane];
            float a = acc6[cc];
            dotxd = fmaf(xc, a, dotxd);
            sd2 = fmaf(a, a, sd2);
            float u = xc - a;
            sdf2 = fmaf(u, u, sdf2);
            xw[cc * CSTR + lane] = a;
        }
        #pragma unroll
        for (int k = 0; k < 3; ++k) {
            int flat = lane + (k << 6);
            int r = flat / 3, c2 = flat % 3;
            float2 o;
            o.x = xw[(c2 << 1) * CSTR + r];
            o.y = xw[((c2 << 1) + 1) * CSTR + r];
            *(float2*)(drow + (size_t)r * DIN + 112 + (c2 << 1)) = o;
        }
    }

    // ---- z features ----
    float xn = sqrtf(sx2);
    float dn = sqrtf(sd2);
    float rel = sqrtf(sdf2) / fmaxf(xn, 1e-10f);
    float cs = dotxd / fmaxf(xn * dn, 1e-10f);
    float mean = sx * (1.0f / DIN);
    float var = fmaxf(sx2 * (1.0f / DIN) - mean * mean, 0.f);
    float stdv = sqrtf(var);
    float zc[4] = {enc, rel, cs, stdv};
    const int sample = rowbase + lane;
    ((float4*)zbuf)[sample] = make_float4(zc[0], zc[1], zc[2], zc[3]);

    // ---- estimation net (4 -> 10 tanh -> 2) + softmax ----
    float l0 = tb1[0], l1 = tb1[1];
    #pragma unroll
    for (int j = 0; j < 10; ++j) {
        float a = tb0[j];
        #pragma unroll
        for (int c = 0; c < 4; ++c) a = fmaf(zc[c], tW0[c * 10 + j], a);
        float t = fast_tanh(a);
        l0 = fmaf(t, tW1[j * 2 + 0], l0);
        l1 = fmaf(t, tW1[j * 2 + 1], l1);
    }
    float lm = fmaxf(l0, l1);
    float e0 = __expf(l0 - lm), e1 = __expf(l1 - lm);
    float inv = 1.0f / (e0 + e1);
    float gam[2] = {e0 * inv, e1 * inv};

    // ---- GMM moments: in-wave reduce -> per-wave LDS -> in-block reduce -> atomics ----
    {
        double zd[4];
        #pragma unroll
        for (int c = 0; c < 4; ++c) zd[c] = (double)zc[c];
        int idx = 0;
        #pragma unroll
        for (int k = 0; k < 2; ++k) {
            double g = (double)gam[k];
            wave_reduce_store(g, &sred[w][idx], lane); idx++;
            double gz[4];
            #pragma unroll
            for (int c = 0; c < 4; ++c) {
                gz[c] = g * zd[c];
                wave_reduce_store(gz[c], &sred[w][idx], lane); idx++;
            }
            #pragma unroll
            for (int c = 0; c < 4; ++c) {
                #pragma unroll
                for (int d = c; d < 4; ++d) {
                    wave_reduce_store(gz[c] * zd[d], &sred[w][idx], lane); idx++;
                }
            }
        }
    }
    __syncthreads();
    // cross-wave reduce -> one atomic per block per slot (30k atomics total)
    if (tid < 30) {
        double s = 0.0;
        #pragma unroll
        for (int w2 = 0; w2 < 8; ++w2) s += sred[w2][tid];
        atomicAdd(&acc[tid], s);
    }
}

__global__ __launch_bounds__(64) void gmm_kernel(
    const double* __restrict__ acc, const float* __restrict__ zbuf,
    float* __restrict__ params, float* __restrict__ covdiag_out)
{
    if (threadIdx.x != 0) return;
    const double TWO_PI = 6.283185307179586;
    double covdiag_sum = 0.0;
    double mu_all[2][4], R_all[2][4], c_all[2];
    for (int k = 0; k < 2; ++k) {
        const double* a = acc + k * 15;
        double Sg = a[0];
        double mu[4];
        for (int c = 0; c < 4; ++c) mu[c] = a[1 + c] / Sg;
        double M[4][4];
        int idx = 5;
        for (int c = 0; c < 4; ++c)
            for (int d = c; d < 4; ++d) {
                double v = a[idx++] / Sg - mu[c] * mu[d];
                M[c][d] = v; M[d][c] = v;
            }
        for (int c = 0; c < 4; ++c) M[c][c] += 1e-12;
        for (int c = 0; c < 4; ++c) covdiag_sum += 1.0 / M[c][c];
        // Gauss-Jordan inverse with partial pivoting; det from pivots
        double A[4][4], inv4[4][4];
        for (int r = 0; r < 4; ++r)
            for (int c = 0; c < 4; ++c) { A[r][c] = M[r][c]; inv4[r][c] = (r == c) ? 1.0 : 0.0; }
        double det = 1.0;
        for (int col = 0; col < 4; ++col) {
            int piv = col;
            for (int r = col + 1; r < 4; ++r)
                if (fabs(A[r][col]) > fabs(A[piv][col])) piv = r;
            if (piv != col) {
                for (int c = 0; c < 4; ++c) {
                    double t = A[col][c]; A[col][c] = A[piv][c]; A[piv][c] = t;
                    t = inv4[col][c]; inv4[col][c] = inv4[piv][c]; inv4[piv][c] = t;
                }
                det = -det;
            }
            double p = A[col][col];
            det *= p;
            double ip = 1.0 / p;
            for (int c = 0; c < 4; ++c) { A[col][c] *= ip; inv4[col][c] *= ip; }
            for (int r = 0; r < 4; ++r) if (r != col) {
                double f = A[r][col];
                for (int c = 0; c < 4; ++c) { A[r][c] -= f * A[col][c]; inv4[r][c] -= f * inv4[col][c]; }
            }
        }
        double det_cov = det * TWO_PI * TWO_PI * TWO_PI * TWO_PI;
        double phi = Sg / (double)BATCH;
        c_all[k] = phi / (sqrt(det_cov) + 1e-12);
        for (int g = 0; g < 4; ++g) {
            R_all[k][g] = inv4[g][0] + inv4[g][1] + inv4[g][2] + inv4[g][3];
            mu_all[k][g] = mu[g];
        }
    }
    // max_val quirk: from sample 0 only
    float4 z0 = *(const float4*)zbuf;
    double z0d[4] = {z0.x, z0.y, z0.z, z0.w};
    double mv = 0.0;
    for (int k = 0; k < 2; ++k) {
        double t = 0.0, inr = 0.0;
        for (int g = 0; g < 4; ++g) {
            double d = z0d[g] - mu_all[k][g];
            t += d; inr += d * R_all[k][g];
        }
        double e = -0.5 * inr * t;
        if (e > mv) mv = e;
    }
    for (int k = 0; k < 2; ++k) {
        for (int g = 0; g < 4; ++g) {
            params[k * 9 + g] = (float)mu_all[k][g];
            params[k * 9 + 4 + g] = (float)R_all[k][g];
        }
        params[k * 9 + 8] = (float)c_all[k];
    }
    params[18] = (float)mv;
    covdiag_out[0] = (float)covdiag_sum;
}

__global__ __launch_bounds__(256) void energy_kernel(
    const float4* __restrict__ zbuf, const float* __restrict__ params,
    float* __restrict__ energy_out)
{
    int b = blockIdx.x * blockDim.x + threadIdx.x;
    float4 z = zbuf[b];
    float mv = params[18];
    float s = 0.f;
    #pragma unroll
    for (int k = 0; k < 2; ++k) {
        const float* p = params + k * 9;
        float d0 = z.x - p[0], d1 = z.y - p[1], d2 = z.z - p[2], d3 = z.w - p[3];
        float t = d0 + d1 + d2 + d3;
        float inr = d0 * p[4] + d1 * p[5] + d2 * p[6] + d3 * p[7];
        float e = -0.5f * inr * t - mv;
        e = fminf(fmaxf(e, -50.f), 50.f);
        s = fmaf(p[8], __expf(e), s);
    }
    energy_out[b] = -mv - __logf(s + 1e-12f);
}

extern "C" void kernel_launch(void* const* d_in, const int* in_sizes, int n_in,
                              void* d_out, int out_size, void* d_ws, size_t ws_size,
                              hipStream_t stream) {
    const float* x   = (const float*)d_in[0];
    const float* eW0 = (const float*)d_in[1];
    const float* eb0 = (const float*)d_in[2];
    const float* eW1 = (const float*)d_in[3];
    const float* eb1 = (const float*)d_in[4];
    const float* eW2 = (const float*)d_in[5];
    const float* eb2 = (const float*)d_in[6];
    const float* eW3 = (const float*)d_in[7];
    const float* eb3 = (const float*)d_in[8];
    const float* dW0 = (const float*)d_in[9];
    const float* db0 = (const float*)d_in[10];
    const float* dW1 = (const float*)d_in[11];
    const float* db1 = (const float*)d_in[12];
    const float* dW2 = (const float*)d_in[13];
    const float* db2 = (const float*)d_in[14];
    const float* dW3 = (const float*)d_in[15];
    const float* db3 = (const float*)d_in[16];
    const float* tW0 = (const float*)d_in[17];
    const float* tb0 = (const float*)d_in[18];
    const float* tW1 = (const float*)d_in[19];
    const float* tb1 = (const float*)d_in[20];

    float* out = (float*)d_out;
    float* dec_out = out;                                 // [B,118]
    float* energy_out = out + (size_t)BATCH * DIN;        // [B]
    float* covdiag_out = out + (size_t)BATCH * (DIN + 1); // scalar

    char* ws = (char*)d_ws;
    float* zbuf = (float*)ws;                                  // B * 4 floats
    double* acc = (double*)(ws + (size_t)BATCH * 16);          // 30 doubles
    float* params = (float*)(ws + (size_t)BATCH * 16 + 512);   // 19 floats

    hipMemsetAsync(acc, 0, 30 * sizeof(double), stream);

    fwd_kernel<<<NBLK, TPB, 0, stream>>>(
        x, eW0, eb0, eW1, eb1, eW2, eb2, eW3, eb3,
        dW0, db0, dW1, db1, dW2, db2, dW3, db3,
        tW0, tb0, tW1, tb1, dec_out, zbuf, acc);
    gmm_kernel<<<1, 64, 0, stream>>>(acc, zbuf, params, covdiag_out);
    energy_kernel<<<BATCH / 256, 256, 0, stream>>>((const float4*)zbuf, params, energy_out);
}